// Round 1
// baseline (146.630 us; speedup 1.0000x reference)
//
#include <hip/hip_runtime.h>

// Upsample-2x + 4-tap [1,3,3,1]^2 blur (upfirdn2d), f32.
// in : (16,128,128,128)  -> 2048 images of 128x128
// out: (16,128,256,256)  -> 2048 images of 256x256
//
// Each output pixel = weighted sum of a 2x2 input neighborhood:
//   oy even: rows oy/2-1 (w1), oy/2 (w3); oy odd: rows (oy-1)/2 (w3), (oy+1)/2 (w1)
//   same along x; total weight (wy*wx)/64; out-of-range inputs are zero.
//
// Mapping: one 64-lane wave == one output row. Lane xq covers ox=4xq..4xq+3,
// which needs input x-values 2xq-1..2xq+2. Lane loads float2 (b,c)=x[2xq],x[2xq+1]
// per row; halo a=x[2xq-1], d=x[2xq+2] come from neighbor lanes via shfl.

__global__ __launch_bounds__(256) void blur_up2_kernel(
    const float* __restrict__ in, float* __restrict__ out) {
  const int tid = threadIdx.x;
  const int xq = tid & 63;        // x quad index: ox = 4*xq + {0..3}
  const int ry = tid >> 6;        // which of 4 rows this block covers
  const int img = blockIdx.x >> 6;       // (b*128 + c) in [0,2048)
  const int rowgroup = blockIdx.x & 63;  // 64 rowgroups of 4 rows
  const int oy = rowgroup * 4 + ry;      // output row in [0,256)

  // y taps
  const int j = oy >> 1;
  int iy0, iy1;
  float wy0, wy1;
  if ((oy & 1) == 0) { iy0 = j - 1; wy0 = 1.f; iy1 = j;     wy1 = 3.f; }
  else               { iy0 = j;     wy0 = 3.f; iy1 = j + 1; wy1 = 1.f; }
  if (iy0 < 0)   { iy0 = 0;   wy0 = 0.f; }
  if (iy1 > 127) { iy1 = 127; wy1 = 0.f; }

  const float* base = in + (size_t)img * (128 * 128);
  const float2 bc0 = ((const float2*)(base + iy0 * 128))[xq];
  const float2 bc1 = ((const float2*)(base + iy1 * 128))[xq];

  // halo via wave shuffles (wave = 64 lanes = exactly this row)
  float a0 = __shfl_up(bc0.y, 1);   // x[2xq-1] from lane xq-1
  float d0 = __shfl_down(bc0.x, 1); // x[2xq+2] from lane xq+1
  float a1 = __shfl_up(bc1.y, 1);
  float d1 = __shfl_down(bc1.x, 1);
  if (xq == 0)  { a0 = 0.f; a1 = 0.f; }   // ix=-1 -> zero
  if (xq == 63) { d0 = 0.f; d1 = 0.f; }   // ix=128 -> zero

  // per-row horizontal combines for ox = 4xq + {0,1,2,3}
  const float r00 = a0 + 3.f * bc0.x;
  const float r01 = 3.f * bc0.x + bc0.y;
  const float r02 = bc0.x + 3.f * bc0.y;
  const float r03 = 3.f * bc0.y + d0;

  const float r10 = a1 + 3.f * bc1.x;
  const float r11 = 3.f * bc1.x + bc1.y;
  const float r12 = bc1.x + 3.f * bc1.y;
  const float r13 = 3.f * bc1.y + d1;

  const float s = 1.f / 64.f;
  float4 o;
  o.x = (wy0 * r00 + wy1 * r10) * s;
  o.y = (wy0 * r01 + wy1 * r11) * s;
  o.z = (wy0 * r02 + wy1 * r12) * s;
  o.w = (wy0 * r03 + wy1 * r13) * s;

  ((float4*)(out + (size_t)img * (256 * 256) + (size_t)oy * 256))[xq] = o;
}

extern "C" void kernel_launch(void* const* d_in, const int* in_sizes, int n_in,
                              void* d_out, int out_size, void* d_ws, size_t ws_size,
                              hipStream_t stream) {
  const float* x = (const float*)d_in[0];
  float* out = (float*)d_out;
  // 2048 images * 64 rowgroups = 131072 blocks; 256 threads = 4 waves = 4 rows
  dim3 grid(2048 * 64);
  dim3 block(256);
  blur_up2_kernel<<<grid, block, 0, stream>>>(x, out);
}

// Round 2
// 101.246 us; speedup vs baseline: 1.4482x; 1.4482x over previous
//
#include <hip/hip_runtime.h>

// Upsample-2x + 4-tap [1,3,3,1]^2 blur (upfirdn2d), f32.
// in : (16,128,128,128)  out: (16,128,256,256)
//
// One 64-lane wave produces 8 output rows (oy = 8q..8q+7) of one image from
// 6 input rows (4q-1 .. 4q+4) held in registers. Lane xq covers output
// columns 4xq..4xq+3 from input floats x[2xq],x[2xq+1] (float2 load) plus
// halo x[2xq-1],x[2xq+2] via wave shuffles.
//
// Vertical taps: oy even -> rows oy/2-1 (w1), oy/2 (w3); odd -> (oy-1)/2 (w3),
// (oy+1)/2 (w1). Horizontal identical. Scale 1/64. OOB rows/cols are zero.
//
// Output is write-only 512MB -> nontemporal stores (don't allocate in L2,
// keep L2 for the 4x-reused input rows).

typedef float f32x4 __attribute__((ext_vector_type(4)));

__global__ __launch_bounds__(256) void blur_up2_kernel(
    const float* __restrict__ in, float* __restrict__ out) {
  const int tid = threadIdx.x;
  const int xq = tid & 63;          // lane: output cols 4xq..4xq+3
  const int wv = tid >> 6;          // wave in block: 0..3
  const int img = blockIdx.x >> 3;  // (b*128+c) in [0,2048)
  const int qg  = blockIdx.x & 7;   // q-group
  const int q   = qg * 4 + wv;      // [0,32): wave's 8 output rows = 8q..8q+7

  const float* base = in + (size_t)img * (128 * 128);
  const int r0 = 4 * q - 1;         // input rows r0 .. r0+5

  // --- load 6 input rows (float2 per lane), clamped; zero true-OOB rows ---
  float2 v[6];
#pragma unroll
  for (int k = 0; k < 6; ++k) {
    int r = r0 + k;
    int rc = r < 0 ? 0 : (r > 127 ? 127 : r);
    v[k] = ((const float2*)(base + rc * 128))[xq];
  }
  if (q == 0)  { v[0].x = 0.f; v[0].y = 0.f; }   // row -1
  if (q == 31) { v[5].x = 0.f; v[5].y = 0.f; }   // row 128

  // --- horizontal combine per row: h[k][c] for output cols 4xq+c ---
  float h[6][4];
#pragma unroll
  for (int k = 0; k < 6; ++k) {
    float a = __shfl_up(v[k].y, 1);    // x[2xq-1]
    float d = __shfl_down(v[k].x, 1);  // x[2xq+2]
    if (xq == 0)  a = 0.f;
    if (xq == 63) d = 0.f;
    h[k][0] = a + 3.f * v[k].x;
    h[k][1] = 3.f * v[k].x + v[k].y;
    h[k][2] = v[k].x + 3.f * v[k].y;
    h[k][3] = 3.f * v[k].y + d;
  }

  // --- vertical combine + nontemporal store, 8 output rows ---
  float* obase = out + (size_t)img * (256 * 256) + (size_t)(8 * q) * 256;
  const float s = 1.f / 64.f;
#pragma unroll
  for (int t = 0; t < 8; ++t) {
    const int kA = (t + 1) >> 1;     // rows (r0+kA, r0+kA+1)
    const int kB = kA + 1;
    const float wA = (t & 1) ? 3.f : 1.f;
    const float wB = (t & 1) ? 1.f : 3.f;
    f32x4 o;
    o.x = (wA * h[kA][0] + wB * h[kB][0]) * s;
    o.y = (wA * h[kA][1] + wB * h[kB][1]) * s;
    o.z = (wA * h[kA][2] + wB * h[kB][2]) * s;
    o.w = (wA * h[kA][3] + wB * h[kB][3]) * s;
    __builtin_nontemporal_store(o, (f32x4*)(obase + t * 256) + xq);
  }
}

extern "C" void kernel_launch(void* const* d_in, const int* in_sizes, int n_in,
                              void* d_out, int out_size, void* d_ws, size_t ws_size,
                              hipStream_t stream) {
  const float* x = (const float*)d_in[0];
  float* out = (float*)d_out;
  // 2048 images * 8 q-groups = 16384 blocks; 256 threads = 4 waves = 32 rows
  dim3 grid(2048 * 8);
  dim3 block(256);
  blur_up2_kernel<<<grid, block, 0, stream>>>(x, out);
}